// Round 4
// baseline (82.752 us; speedup 1.0000x reference)
//
#include <hip/hip_runtime.h>
#include <math.h>

#define STPB 1024     // k_setup threads (single block)
#define PPTB 256      // k_pairs threads per block
#define SPLIT 32      // lanes per particle in k_pairs
#define MAXPER 8      // max particles per setup thread (N <= 8192)
#define NCELL 9
#define NCELL3 729
#define PI_F 3.14159265358979323846f
#define EPS_F 1e-12f

__device__ __forceinline__ float wave_reduce(float v) {
#pragma unroll
    for (int off = 32; off > 0; off >>= 1) v += __shfl_down(v, off, 64);
    return v;
}

// valid on thread 0 only; all threads must call
__device__ __forceinline__ float block_reduce(float v, float* sbuf, int nwaves) {
    v = wave_reduce(v);
    int lane = threadIdx.x & 63;
    int wid  = threadIdx.x >> 6;
    if (lane == 0) sbuf[wid] = v;
    __syncthreads();
    float r = 0.0f;
    if (threadIdx.x == 0) {
        for (int w = 0; w < nwaves; ++w) r += sbuf[w];
    }
    return r;
}

__device__ __forceinline__ int cell_coord(float x) {
    int c = (int)floorf(x * (float)NCELL);
    return min(max(c, 0), NCELL - 1);
}

// ---- K1: setup — pos/vel, loss1 sum, histogram, 2-barrier scan, scatter ----
__global__ void __launch_bounds__(STPB) k_setup(
    const float* __restrict__ pred, const float* __restrict__ y,
    const float* __restrict__ mid_pos, const float* __restrict__ mid_vel,
    const float* __restrict__ y_mean, const float* __restrict__ y_std,
    const float* __restrict__ dt_p, const int* __restrict__ nb_p,
    float4* __restrict__ pos_s, float2* __restrict__ vel_s,
    int* __restrict__ cell_start, float* __restrict__ l1sum,
    int* __restrict__ ticket, int N)
{
    __shared__ int s_cnt[NCELL3];
    __shared__ int s_cur[NCELL3];
    __shared__ int s_wsum[STPB / 64];
    __shared__ float sbuf[STPB / 64];

    int tid = threadIdx.x;
    if (tid == 0) ticket[0] = 0;           // graph-replay-safe init (ws not re-poisoned)
    for (int c = tid; c < NCELL3; c += STPB) s_cnt[c] = 0;
    __syncthreads();

    int nb = nb_p[0];
    float inv_dt = 1.0f / dt_p[0];
    float ym0 = y_mean[0], ym1 = y_mean[1], ym2 = y_mean[2];
    float ys0 = y_std[0],  ys1 = y_std[1],  ys2 = y_std[2];

    float px[MAXPER], py[MAXPER], pz[MAXPER];
    float vx[MAXPER], vy[MAXPER], vz[MAXPER];
    int   ci[MAXPER];
    float t1 = 0.0f;

#pragma unroll
    for (int k = 0; k < MAXPER; ++k) {
        int i = tid + k * STPB;
        ci[k] = -1;
        if (i < N) {
            float y0 = y[i * 3 + 0], y1 = y[i * 3 + 1], y2 = y[i * 3 + 2];
            float p0 = pred[i * 3 + 0], p1 = pred[i * 3 + 1], p2 = pred[i * 3 + 2];
            float d0 = y0 - p0, d1 = y1 - p1, d2 = y2 - p2;
            t1 = fmaf(d0, d0, fmaf(d1, d1, fmaf(d2, d2, t1)));
            bool fluid = (i >= nb);
            float i0 = fluid ? fmaf(y0, ys0, ym0) : 0.0f;
            float i1 = fluid ? fmaf(y1, ys1, ym1) : 0.0f;
            float i2 = fluid ? fmaf(y2, ys2, ym2) : 0.0f;
            px[k] = mid_pos[i * 3 + 0] + i0;
            py[k] = mid_pos[i * 3 + 1] + i1;
            pz[k] = mid_pos[i * 3 + 2] + i2;
            vx[k] = mid_vel[i * 3 + 0] + i0 * inv_dt;
            vy[k] = mid_vel[i * 3 + 1] + i1 * inv_dt;
            vz[k] = mid_vel[i * 3 + 2] + i2 * inv_dt;
            int cx = cell_coord(px[k]), cy = cell_coord(py[k]), cz = cell_coord(pz[k]);
            ci[k] = (cx * NCELL + cy) * NCELL + cz;
            atomicAdd(&s_cnt[ci[k]], 1);
        }
    }
    __syncthreads();

    // exclusive scan over 729 counts: wave shfl-scan + serial scan of 16 wave sums
    int lane = tid & 63, wid = tid >> 6;
    int myc = (tid < NCELL3) ? s_cnt[tid] : 0;
    int v = myc;
#pragma unroll
    for (int off = 1; off < 64; off <<= 1) {
        int u = __shfl_up(v, off, 64);
        if (lane >= off) v += u;
    }
    if (lane == 63) s_wsum[wid] = v;
    __syncthreads();
    if (tid == 0) {
        int acc = 0;
        for (int w = 0; w < STPB / 64; ++w) { int t = s_wsum[w]; s_wsum[w] = acc; acc += t; }
    }
    __syncthreads();
    int incl = v + s_wsum[wid];
    if (tid < NCELL3) {
        int start = incl - myc;            // exclusive prefix
        s_cur[tid] = start;
        cell_start[tid] = start;
    }
    if (tid == 0) cell_start[NCELL3] = N;
    __syncthreads();

    // scatter (counting sort); within-cell order atomic-racy -> fp jitter only
#pragma unroll
    for (int k = 0; k < MAXPER; ++k) {
        if (ci[k] >= 0) {
            int dst = atomicAdd(&s_cur[ci[k]], 1);
            pos_s[dst] = make_float4(px[k], py[k], pz[k], vx[k]);
            vel_s[dst] = make_float2(vy[k], vz[k]);
        }
    }

    float s = block_reduce(t1, sbuf, STPB / 64);
    if (tid == 0) l1sum[0] = s;
}

// ---- K2: cell-list pairs (32 lanes/particle, column-merged coalesced ranges)
//      + fused final combine via last-block ticket ----
__global__ void __launch_bounds__(PPTB) k_pairs(
    const float4* __restrict__ pos_s, const float2* __restrict__ vel_s,
    const int* __restrict__ cell_start,
    const float* __restrict__ h_p, const float* __restrict__ vol_p,
    const float* __restrict__ l1sum,
    float* __restrict__ l2part, float* __restrict__ l3part,
    int* __restrict__ ticket, float* __restrict__ out,
    int N, int nblk, float invN)
{
    __shared__ float sbufA[PPTB / 64];
    __shared__ float sbufB[PPTB / 64];
    __shared__ int s_ticket;

    int t = blockIdx.x * PPTB + threadIdx.x;
    int p = t >> 5;          // particle (sorted index)
    int s = t & (SPLIT - 1);

    float h = h_p[0];
    float inv_h = 1.0f / h;
    float h2 = h * h;

    float wacc = 0.0f, dacc = 0.0f;

    if (p < N) {
        float4 me4 = pos_s[p];
        float2 me2 = vel_s[p];
        float xix = me4.x, xiy = me4.y, xiz = me4.z;
        float vix = me4.w, viy = me2.x, viz = me2.y;
        int cx = cell_coord(xix), cy = cell_coord(xiy), cz = cell_coord(xiz);
        int xlo = max(cx - 1, 0), xhi = min(cx + 1, NCELL - 1);
        int ylo = max(cy - 1, 0), yhi = min(cy + 1, NCELL - 1);
        int zlo = max(cz - 1, 0), zhi = min(cz + 1, NCELL - 1);

        for (int nx = xlo; nx <= xhi; ++nx) {
            for (int ny = ylo; ny <= yhi; ++ny) {
                int base = (nx * NCELL + ny) * NCELL;
                int j0 = cell_start[base + zlo];
                int j1 = cell_start[base + zhi + 1];   // 3 z-cells contiguous
                for (int j = j0 + s; j < j1; j += SPLIT) {
                    float4 a = pos_s[j];
                    float dx = xix - a.x, dy = xiy - a.y, dz = xiz - a.z;
                    float d2 = fmaf(dx, dx, fmaf(dy, dy, dz * dz));
                    if (d2 > h2) continue;
                    float2 b = vel_s[j];
                    float r2c = fmaxf(d2, EPS_F);
                    float ir  = rsqrtf(r2c);
                    float r   = r2c * ir;
                    float q   = r * inv_h;

                    bool in_mask = (q <= 1.0f);
                    bool lo      = (q <= 0.5f);

                    float q2  = q * q;
                    float om  = 1.0f - q;
                    float om2 = om * om;

                    float w_lo = fmaf(6.0f, q2 * q - q2, 1.0f);   // 6(q^3-q^2)+1
                    float w_hi = 2.0f * om2 * om;                  // 2(1-q)^3
                    float w = lo ? w_lo : w_hi;
                    wacc += in_mask ? w : 0.0f;

                    float dw_lo = q * fmaf(18.0f, q, -12.0f);      // 6q(3q-2)
                    float dw_hi = -6.0f * om2;                     // -6(1-q)^2
                    float dw = lo ? dw_lo : dw_hi;
                    dw = in_mask ? dw : 0.0f;

                    float irm = (d2 > EPS_F) ? ir : 0.0f;
                    float dvx = a.w - vix, dvy = b.x - viy, dvz = b.y - viz;
                    float dot = fmaf(dvx, dx, fmaf(dvy, dy, dvz * dz));
                    dacc = fmaf(dw * irm, dot, dacc);
                }
            }
        }
    }

    // reduce over the 32-lane split group
#pragma unroll
    for (int off = 1; off < SPLIT; off <<= 1) {
        wacc += __shfl_xor(wacc, off, SPLIT);
        dacc += __shfl_xor(dacc, off, SPLIT);
    }

    float aA = 0.0f, bB = 0.0f;
    if (s == 0 && p < N) {
        float vol = vol_p[0];
        float sigma = 8.0f / (PI_F * h * h * h);
        aA = fabsf(fmaf(vol * sigma, wacc, -1.0f));   // |rho/rho0 - 1|
        bB = fabsf(vol * (sigma / h) * dacc);          // |div|
    }
    float sA = block_reduce(aA, sbufA, PPTB / 64);
    __syncthreads();
    float sB = block_reduce(bB, sbufB, PPTB / 64);
    if (threadIdx.x == 0) { l2part[blockIdx.x] = sA; l3part[blockIdx.x] = sB; }

    // last-block combine
    __threadfence();
    if (threadIdx.x == 0) s_ticket = atomicAdd(ticket, 1);
    __syncthreads();
    if (s_ticket == nblk - 1) {
        __threadfence();
        float s2 = 0.0f, s3 = 0.0f;
        for (int k = threadIdx.x; k < nblk; k += PPTB) {
            s2 += l2part[k]; s3 += l3part[k];
        }
        __syncthreads();
        float r2 = block_reduce(s2, sbufA, PPTB / 64);
        __syncthreads();
        float r3 = block_reduce(s3, sbufB, PPTB / 64);
        if (threadIdx.x == 0) {
            out[0] = l1sum[0] * invN + 0.1f * (r2 * invN) + 0.1f * (r3 * invN);
        }
    }
}

extern "C" void kernel_launch(void* const* d_in, const int* in_sizes, int n_in,
                              void* d_out, int out_size, void* d_ws, size_t ws_size,
                              hipStream_t stream) {
    const float* pred    = (const float*)d_in[0];
    const float* y       = (const float*)d_in[1];
    const float* mid_pos = (const float*)d_in[2];
    const float* mid_vel = (const float*)d_in[3];
    const float* y_mean  = (const float*)d_in[4];
    const float* y_std   = (const float*)d_in[5];
    const float* h_p     = (const float*)d_in[6];
    const float* vol_p   = (const float*)d_in[7];
    // d_in[8] = rho_0 (cancels algebraically)
    const float* dt_p    = (const float*)d_in[9];
    const int*   nb_p    = (const int*)d_in[10];

    int N = in_sizes[0] / 3;
    int nblk = (N * SPLIT + PPTB - 1) / PPTB;

    char* wsb = (char*)d_ws;
    float4* pos_s   = (float4*)wsb;                       wsb += (size_t)N * sizeof(float4);
    float2* vel_s   = (float2*)wsb;                       wsb += (size_t)N * sizeof(float2);
    int*    cell_st = (int*)wsb;                          wsb += (NCELL3 + 1) * sizeof(int);
    int*    ticket  = (int*)wsb;                          wsb += sizeof(int);
    float*  l1sum   = (float*)wsb;                        wsb += sizeof(float);
    float*  l2part  = (float*)wsb;                        wsb += (size_t)nblk * sizeof(float);
    float*  l3part  = (float*)wsb;

    k_setup<<<1, STPB, 0, stream>>>(pred, y, mid_pos, mid_vel, y_mean, y_std,
                                    dt_p, nb_p, pos_s, vel_s, cell_st, l1sum,
                                    ticket, N);

    k_pairs<<<nblk, PPTB, 0, stream>>>(pos_s, vel_s, cell_st, h_p, vol_p, l1sum,
                                       l2part, l3part, ticket, (float*)d_out,
                                       N, nblk, 1.0f / (float)N);
}

// Round 5
// 31.188 us; speedup vs baseline: 2.6533x; 2.6533x over previous
//
#include <hip/hip_runtime.h>
#include <math.h>

#define STPB 1024     // k_setup threads (single block)
#define PPTB 256      // k_pairs threads per block
#define SPLIT 16      // lanes per home particle
#define NGRP (PPTB / SPLIT)
#define MAXPER 8      // max particles per setup thread (N <= 8192)
#define NCELL 9
#define NCELL3 729
#define CAP 2048      // LDS staging capacity (particles); fallback if exceeded
#define PI_F 3.14159265358979323846f
#define EPS_F 1e-12f

__device__ __forceinline__ float wave_reduce(float v) {
#pragma unroll
    for (int off = 32; off > 0; off >>= 1) v += __shfl_down(v, off, 64);
    return v;
}

// valid on thread 0 only; all threads must call
__device__ __forceinline__ float block_reduce(float v, float* sbuf, int nwaves) {
    v = wave_reduce(v);
    int lane = threadIdx.x & 63;
    int wid  = threadIdx.x >> 6;
    if (lane == 0) sbuf[wid] = v;
    __syncthreads();
    float r = 0.0f;
    if (threadIdx.x == 0) {
        for (int w = 0; w < nwaves; ++w) r += sbuf[w];
    }
    return r;
}

__device__ __forceinline__ int cell_coord(float x) {
    int c = (int)floorf(x * (float)NCELL);
    return min(max(c, 0), NCELL - 1);
}

// branchless pair contribution
__device__ __forceinline__ void pair_acc(float xix, float xiy, float xiz,
                                         float vix, float viy, float viz,
                                         const float4& a, const float2& b2,
                                         float inv_h, float h2,
                                         float& wacc, float& dacc) {
    float dx = xix - a.x, dy = xiy - a.y, dz = xiz - a.z;
    float d2 = fmaf(dx, dx, fmaf(dy, dy, dz * dz));
    float r2c = fmaxf(d2, EPS_F);
    float ir  = rsqrtf(r2c);
    float r   = r2c * ir;
    float q   = r * inv_h;
    bool inm = (d2 <= h2) && (q <= 1.0f);
    bool lo  = (q <= 0.5f);
    float q2 = q * q, om = 1.0f - q, om2 = om * om;
    float w  = lo ? fmaf(6.0f, q2 * q - q2, 1.0f) : 2.0f * om2 * om;
    wacc += inm ? w : 0.0f;
    float dw = lo ? q * fmaf(18.0f, q, -12.0f) : -6.0f * om2;
    dw = inm ? dw : 0.0f;
    float irm = (d2 > EPS_F) ? ir : 0.0f;
    float dvx = a.w - vix, dvy = b2.x - viy, dvz = b2.y - viz;
    float dot = fmaf(dvx, dx, fmaf(dvy, dy, dvz * dz));
    dacc = fmaf(dw * irm, dot, dacc);
}

// ---- K1: setup — pos/vel, loss1 -> out[0], histogram, 2-barrier scan, scatter ----
__global__ void __launch_bounds__(STPB) k_setup(
    const float* __restrict__ pred, const float* __restrict__ y,
    const float* __restrict__ mid_pos, const float* __restrict__ mid_vel,
    const float* __restrict__ y_mean, const float* __restrict__ y_std,
    const float* __restrict__ dt_p, const int* __restrict__ nb_p,
    float4* __restrict__ pos_s, float2* __restrict__ vel_s,
    int* __restrict__ cell_start, float* __restrict__ out,
    int N, float invN)
{
    __shared__ int s_cnt[NCELL3];
    __shared__ int s_cur[NCELL3];
    __shared__ int s_wsum[STPB / 64];
    __shared__ float sbuf[STPB / 64];

    int tid = threadIdx.x;
    for (int c = tid; c < NCELL3; c += STPB) s_cnt[c] = 0;
    __syncthreads();

    int nb = nb_p[0];
    float inv_dt = 1.0f / dt_p[0];
    float ym0 = y_mean[0], ym1 = y_mean[1], ym2 = y_mean[2];
    float ys0 = y_std[0],  ys1 = y_std[1],  ys2 = y_std[2];

    float px[MAXPER], py[MAXPER], pz[MAXPER];
    float vx[MAXPER], vy[MAXPER], vz[MAXPER];
    int   ci[MAXPER];
    float t1 = 0.0f;

#pragma unroll
    for (int k = 0; k < MAXPER; ++k) {
        int i = tid + k * STPB;
        ci[k] = -1;
        if (i < N) {
            float y0 = y[i * 3 + 0], y1 = y[i * 3 + 1], y2 = y[i * 3 + 2];
            float p0 = pred[i * 3 + 0], p1 = pred[i * 3 + 1], p2 = pred[i * 3 + 2];
            float d0 = y0 - p0, d1 = y1 - p1, d2 = y2 - p2;
            t1 = fmaf(d0, d0, fmaf(d1, d1, fmaf(d2, d2, t1)));
            bool fluid = (i >= nb);
            float i0 = fluid ? fmaf(y0, ys0, ym0) : 0.0f;
            float i1 = fluid ? fmaf(y1, ys1, ym1) : 0.0f;
            float i2 = fluid ? fmaf(y2, ys2, ym2) : 0.0f;
            px[k] = mid_pos[i * 3 + 0] + i0;
            py[k] = mid_pos[i * 3 + 1] + i1;
            pz[k] = mid_pos[i * 3 + 2] + i2;
            vx[k] = mid_vel[i * 3 + 0] + i0 * inv_dt;
            vy[k] = mid_vel[i * 3 + 1] + i1 * inv_dt;
            vz[k] = mid_vel[i * 3 + 2] + i2 * inv_dt;
            int cx = cell_coord(px[k]), cy = cell_coord(py[k]), cz = cell_coord(pz[k]);
            ci[k] = (cx * NCELL + cy) * NCELL + cz;
            atomicAdd(&s_cnt[ci[k]], 1);
        }
    }
    __syncthreads();

    // exclusive scan over 729 counts: wave shfl-scan + serial scan of 16 wave sums
    int lane = tid & 63, wid = tid >> 6;
    int myc = (tid < NCELL3) ? s_cnt[tid] : 0;
    int v = myc;
#pragma unroll
    for (int off = 1; off < 64; off <<= 1) {
        int u = __shfl_up(v, off, 64);
        if (lane >= off) v += u;
    }
    if (lane == 63) s_wsum[wid] = v;
    __syncthreads();
    if (tid == 0) {
        int acc = 0;
        for (int w = 0; w < STPB / 64; ++w) { int t = s_wsum[w]; s_wsum[w] = acc; acc += t; }
    }
    __syncthreads();
    int incl = v + s_wsum[wid];
    if (tid < NCELL3) {
        int start = incl - myc;            // exclusive prefix
        s_cur[tid] = start;
        cell_start[tid] = start;
    }
    if (tid == 0) cell_start[NCELL3] = N;
    __syncthreads();

    // scatter (counting sort); within-cell order atomic-racy -> fp jitter only
#pragma unroll
    for (int k = 0; k < MAXPER; ++k) {
        if (ci[k] >= 0) {
            int dst = atomicAdd(&s_cur[ci[k]], 1);
            pos_s[dst] = make_float4(px[k], py[k], pz[k], vx[k]);
            vel_s[dst] = make_float2(vy[k], vz[k]);
        }
    }

    float s = block_reduce(t1, sbuf, STPB / 64);
    if (tid == 0) out[0] = s * invN;   // loss1 term; k_pairs atomicAdds the rest
}

// ---- K2: one block per cell; LDS-staged 27-cell neighborhood; fused combine ----
__global__ void __launch_bounds__(PPTB) k_pairs(
    const float4* __restrict__ pos_s, const float2* __restrict__ vel_s,
    const int* __restrict__ cell_start,
    const float* __restrict__ h_p, const float* __restrict__ vol_p,
    float* __restrict__ out, float coef /* 0.1/N */)
{
    __shared__ float4 sh4[CAP];
    __shared__ float2 sh2[CAP];
    __shared__ float sred[PPTB / 64];

    int b = blockIdx.x;
    int hj0 = cell_start[b];
    int hj1 = cell_start[b + 1];
    if (hj0 >= hj1) return;                 // empty home cell (block-uniform, pre-barrier)

    int tid = threadIdx.x;
    int cz = b % NCELL, cy = (b / NCELL) % NCELL, cx = b / (NCELL * NCELL);
    int zlo = max(cz - 1, 0), zhi = min(cz + 1, NCELL - 1);

    // <=9 contiguous (j0,len) source ranges, all in registers (static unroll)
    int rj0[9], rln[9];
    int T = 0;
#pragma unroll
    for (int r = 0; r < 9; ++r) {
        int nx = cx - 1 + r / 3;
        int ny = cy - 1 + r % 3;
        bool valid = ((unsigned)nx < NCELL) && ((unsigned)ny < NCELL);
        int base = (nx * NCELL + ny) * NCELL;
        int j0 = 0, j1 = 0;
        if (valid) { j0 = cell_start[base + zlo]; j1 = cell_start[base + zhi + 1]; }
        rj0[r] = j0; rln[r] = j1 - j0;
        T += j1 - j0;
    }

    float h = h_p[0], inv_h = 1.0f / h, h2 = h * h;
    float vol = vol_p[0];
    float sigma = 8.0f / (PI_F * h * h * h);

    int grp = tid >> 4;          // 0..15 (SPLIT=16)
    int s   = tid & (SPLIT - 1);
    float acc = 0.0f;

    if (T <= CAP) {
        // stage whole neighborhood once (coalesced, <=9 contiguous ranges)
        int off = 0;
#pragma unroll
        for (int r = 0; r < 9; ++r) {
            int j0 = rj0[r], len = rln[r];
            for (int g = tid; g < len; g += PPTB) {
                sh4[off + g] = pos_s[j0 + g];
                sh2[off + g] = vel_s[j0 + g];
            }
            off += len;
        }
        __syncthreads();

        for (int hb = hj0; hb < hj1; hb += NGRP) {
            int hp = hb + grp;
            bool hv = (hp < hj1);
            int hpc = hv ? hp : hj0;
            float4 me4 = pos_s[hpc];
            float2 me2 = vel_s[hpc];
            float wacc = 0.0f, dacc = 0.0f;
            for (int j = s; j < T; j += SPLIT) {
                pair_acc(me4.x, me4.y, me4.z, me4.w, me2.x, me2.y,
                         sh4[j], sh2[j], inv_h, h2, wacc, dacc);
            }
#pragma unroll
            for (int o = 1; o < SPLIT; o <<= 1) {
                wacc += __shfl_xor(wacc, o, SPLIT);
                dacc += __shfl_xor(dacc, o, SPLIT);
            }
            if (s == 0 && hv) {
                acc += fabsf(fmaf(vol * sigma, wacc, -1.0f))
                     + fabsf(vol * (sigma / h) * dacc);
            }
        }
    } else {
        // pathological density: direct-from-global fallback (correctness path)
        for (int hb = hj0; hb < hj1; hb += NGRP) {
            int hp = hb + grp;
            bool hv = (hp < hj1);
            int hpc = hv ? hp : hj0;
            float4 me4 = pos_s[hpc];
            float2 me2 = vel_s[hpc];
            float wacc = 0.0f, dacc = 0.0f;
#pragma unroll
            for (int r = 0; r < 9; ++r) {
                int j0 = rj0[r], len = rln[r];
                for (int j = s; j < len; j += SPLIT) {
                    pair_acc(me4.x, me4.y, me4.z, me4.w, me2.x, me2.y,
                             pos_s[j0 + j], vel_s[j0 + j], inv_h, h2, wacc, dacc);
                }
            }
#pragma unroll
            for (int o = 1; o < SPLIT; o <<= 1) {
                wacc += __shfl_xor(wacc, o, SPLIT);
                dacc += __shfl_xor(dacc, o, SPLIT);
            }
            if (s == 0 && hv) {
                acc += fabsf(fmaf(vol * sigma, wacc, -1.0f))
                     + fabsf(vol * (sigma / h) * dacc);
            }
        }
        __syncthreads();   // align barrier count before block_reduce
    }

    float tot = block_reduce(acc, sred, PPTB / 64);
    if (tid == 0) atomicAdd(out, coef * tot);   // device-scope, cross-XCD coherent
}

extern "C" void kernel_launch(void* const* d_in, const int* in_sizes, int n_in,
                              void* d_out, int out_size, void* d_ws, size_t ws_size,
                              hipStream_t stream) {
    const float* pred    = (const float*)d_in[0];
    const float* y       = (const float*)d_in[1];
    const float* mid_pos = (const float*)d_in[2];
    const float* mid_vel = (const float*)d_in[3];
    const float* y_mean  = (const float*)d_in[4];
    const float* y_std   = (const float*)d_in[5];
    const float* h_p     = (const float*)d_in[6];
    const float* vol_p   = (const float*)d_in[7];
    // d_in[8] = rho_0 (cancels algebraically)
    const float* dt_p    = (const float*)d_in[9];
    const int*   nb_p    = (const int*)d_in[10];

    int N = in_sizes[0] / 3;
    float invN = 1.0f / (float)N;

    char* wsb = (char*)d_ws;
    float4* pos_s   = (float4*)wsb;                       wsb += (size_t)N * sizeof(float4);
    float2* vel_s   = (float2*)wsb;                       wsb += (size_t)N * sizeof(float2);
    int*    cell_st = (int*)wsb;

    k_setup<<<1, STPB, 0, stream>>>(pred, y, mid_pos, mid_vel, y_mean, y_std,
                                    dt_p, nb_p, pos_s, vel_s, cell_st,
                                    (float*)d_out, N, invN);

    k_pairs<<<NCELL3, PPTB, 0, stream>>>(pos_s, vel_s, cell_st, h_p, vol_p,
                                         (float*)d_out, 0.1f * invN);
}